// Round 2
// baseline (1103.560 us; speedup 1.0000x reference)
//
#include <hip/hip_runtime.h>
#include <hip/hip_bf16.h>

// B=32, S=2048, H=1024, U=1024. M = B*S = 65536 rows.
// score[b,s] = sum_u tanh(enc[b,s,:]@W1[:,u] + W1b[u] + ph[b,u]) * Vw[u]  (+Vb cancels in softmax)
// out = softmax_s(score)

typedef __bf16 bf16x8 __attribute__((ext_vector_type(8)));
typedef float  f32x4  __attribute__((ext_vector_type(4)));

#define HDIM 1024
#define UDIM 1024
#define SDIM 2048
#define MROWS 65536

__device__ inline unsigned short f2bf(float x) {
    return __builtin_bit_cast(unsigned short, (__bf16)x);
}

// fast tanh: tanh(x) = sign(x) * (1-e^{-2|x|})/(1+e^{-2|x|}). z in (0,1].
__device__ inline float fast_tanh(float x) {
    float z = __expf(-2.0f * __builtin_fabsf(x));
    float t = __fdividef(1.0f - z, 1.0f + z);
    return __builtin_copysignf(t, x);
}

// async 16B global->LDS (m97: width=16 emits global_load_lds_dwordx4)
#define GLDS16(gp, lp)                                                              \
    __builtin_amdgcn_global_load_lds(                                               \
        (const __attribute__((address_space(1))) unsigned int*)(gp),                \
        (__attribute__((address_space(3))) unsigned int*)(lp), 16, 0, 0)

// ---------------- prep: W1 [H,U] fp32 -> W1T [U,H] bf16 ----------------
__global__ void w1t_kernel(const float* __restrict__ W1, unsigned short* __restrict__ W1T) {
    __shared__ float tile[32][33];
    int bx = blockIdx.x;   // u tile
    int by = blockIdx.y;   // h tile
    int tx = threadIdx.x, ty = threadIdx.y;   // (32,8)
#pragma unroll
    for (int r = 0; r < 4; ++r) {
        int h = by * 32 + ty + r * 8;
        int u = bx * 32 + tx;
        tile[ty + r * 8][tx] = W1[h * UDIM + u];
    }
    __syncthreads();
#pragma unroll
    for (int r = 0; r < 4; ++r) {
        int u = bx * 32 + ty + r * 8;
        int h = by * 32 + tx;
        W1T[u * HDIM + h] = f2bf(tile[tx][ty + r * 8]);
    }
}

// ---------------- prep: ph partials (split-K over h) ----------------
__global__ void php_kernel(const float* __restrict__ hn, const float* __restrict__ W2,
                           float* __restrict__ php) {
    int u = (blockIdx.x & 3) * 256 + threadIdx.x;
    int b = blockIdx.y;
    int hc = blockIdx.z;           // 8 chunks of 128
    int h0 = hc * 128;
    float acc = 0.f;
#pragma unroll 8
    for (int h = h0; h < h0 + 128; ++h)
        acc = fmaf(hn[b * HDIM + h], W2[h * UDIM + u], acc);
    php[(hc * 32 + b) * UDIM + u] = acc;
}

__global__ void ph_combine(const float* __restrict__ php, const float* __restrict__ W1b,
                           const float* __restrict__ W2b, float* __restrict__ ph) {
    int idx = blockIdx.x * 256 + threadIdx.x;   // 32768
    int u = idx & (UDIM - 1);
    int b = idx >> 10;
    float acc = W1b[u] + W2b[u];
#pragma unroll
    for (int p = 0; p < 8; ++p) acc += php[(p * 32 + b) * UDIM + u];
    ph[idx] = acc;
}

// =======================================================================
// Persistent 8-phase 256x256 fused GEMM, fp32-A direct staging (no cvt pass).
//
// Grid = 256 blocks (1/CU), 512 thr = 8 waves (2M x 4N). Block bx:
//   tile_n = bx&3 (256 u-cols), mgrp = bx>>2 -> rows [mgrp*1024, +1024)
//   = 4 m-tiles processed sequentially; stage lookahead flows across them.
//   Natural dispatch: bx%8 = XCD -> each XCD sees ONE tile_n (B-panel 512KB
//   L2-resident); the 4 n-copies of each A-row run concurrently -> LLC reuse.
//
// LDS (135168 B):
//   A fp32, SINGLE-buffered: A0 [0,32768), A1 [32768,65536). 128 rows x 64
//     floats, 16x16B-chunk XOR swizzle: phys_q = logical_q ^ (row&15).
//     global_load_lds dest linear; global SOURCE pre-swizzled (m173).
//   B bf16, double-buffered: parity0 B0@65536 B1@81920; parity1 @98304/114688.
//     (round-1 verified 8-chunk XOR layout, kept verbatim.)
//   red scratch @131072 (4KB) for the cross-wave epilogue reduce.
//
// Per global K-tile tau (=mt*16+tk, 64 total), quadrants reordered so one
// B-quad is live at a time:
//   p0: read aF0(16xb128 f32 + pack) + bB(j0-1);            MFMA (0-3)x(0-1)
//   p1: read aF1;                    stage B1(tau+1) GLDS;  MFMA (4-7)x(0-1)
//   p2: read bB(j2-3);               stage A(tau+1) 8xGLDS; MFMA (4-7)x(2-3)
//   p3:                              stage B0(tau+2) GLDS;  MFMA (0-3)x(2-3)
//       then ONE counted wait: vmcnt(2) (leaves B0(tau+2) in flight; drains
//       B1(tau+1)+A(tau+1) which p0/p2 of tau+1 read).  vmcnt(0) at tau==62.
// A single-buffer safety: A last read p1... (aF1 at p1? no: aF0@p0, aF1@p1);
//   stage A at p2 = after p1's closing barrier. B0 same-parity overwrite at
//   p3 = after p0's read + 3 barriers. B1 writes opposite parity.
// =======================================================================
__global__ __launch_bounds__(512, 2) void score_kernel3(
    const float* __restrict__ enc, const unsigned short* __restrict__ W1T,
    const float* __restrict__ ph, const float* __restrict__ Vw,
    float* __restrict__ part) {
    __shared__ __align__(16) char smem[135168];

    const int bx = blockIdx.x;
    const int tile_n = bx & 3;
    const int mgrp = bx >> 2;           // 0..63
    const int arow0 = mgrp << 10;       // 1024 rows per block, single batch
    const int col0 = tile_n << 8;

    const int t = threadIdx.x;
    const int lane = t & 63;
    const int wid = t >> 6;
    const int wm = wid >> 2;            // 0..1 (M half)
    const int wn = wid & 3;             // 0..3 (N quarter)

    // ---- B ds_read constants (bf16; round-1 verbatim) ----
    const int e = lane & 7;
    const int cc = lane >> 4;
    const int swz16 = (((cc ^ (e & 3)) | ((e >> 2) << 2)) << 4);
    const int offk0 = ((lane & 15) << 7) + swz16;
    const int bhalf_off = (wn & 1) * 8192;
    const unsigned slotB_q = ((wn & 2) ? 16384u : 0u);

    // ---- A ds_read constants (fp32, 16-chunk XOR) ----
    const int mrow = lane & 15;
    const int akc = (lane >> 4) << 1;                     // k-chunk pair base (0,2,4,6)
    const int abase0 = mrow * 256 + ((akc ^ mrow) << 4);  // byte offset, ks=0
    const unsigned slotA = (unsigned)wm * 32768u;

    // ---- B staging constants (round-1 verbatim) ----
    const int rp0 = (wid << 3) + (lane >> 3);
    const int gswB = ((lane & 7) ^ (rp0 & 7)) << 3;
    const size_t gofB0 = (size_t)rp0 * HDIM + gswB;
    const size_t gofB1 = gofB0 + (size_t)64 * HDIM;
    const unsigned lofB0 = (unsigned)(wid << 10);
    const unsigned lofB1 = lofB0 + 8192u;
    const unsigned short* gB  = W1T + (size_t)col0 * HDIM;
    const unsigned short* gB1g = gB + (size_t)128 * HDIM;

#define BSLOT0(s) (((s) & 1) ? 98304u : 65536u)
#define STAGE_B0(s)                                                          \
    do {                                                                     \
        const unsigned short* gp = gB + (((s) & 15) << 6);                   \
        GLDS16(gp + gofB0, (char*)smem + BSLOT0(s) + lofB0);                 \
        GLDS16(gp + gofB1, (char*)smem + BSLOT0(s) + lofB1);                 \
    } while (0)
#define STAGE_B1(s)                                                          \
    do {                                                                     \
        const unsigned short* gp = gB1g + (((s) & 15) << 6);                 \
        GLDS16(gp + gofB0, (char*)smem + BSLOT0(s) + 16384u + lofB0);        \
        GLDS16(gp + gofB1, (char*)smem + BSLOT0(s) + 16384u + lofB1);        \
    } while (0)
// A: chunk c in [0,2048): r=c>>4, q=c&15; LDS linear at c*16; global source
// pre-swizzled: float offset r*1024 + ((q^(r&15))*4). 8 GLDS = both halves.
#define STAGE_A(s)                                                           \
    do {                                                                     \
        const float* ga = enc +                                              \
            (((size_t)(arow0 + (((s) >> 4) << 8))) << 10) + (((s) & 15) << 6); \
        _Pragma("unroll") for (int i2 = 0; i2 < 4; ++i2) {                   \
            const int ci = (wid << 8) + (i2 << 6) + lane;                    \
            const int ri = ci >> 4, qi = ci & 15;                            \
            const int gof = (ri << 10) + ((qi ^ (ri & 15)) << 2);            \
            GLDS16(ga + gof, (char*)smem + (unsigned)(ci << 4));             \
            GLDS16(ga + 131072 + gof, (char*)smem + 32768u + (unsigned)(ci << 4)); \
        }                                                                    \
    } while (0)
// fp32 frag read + in-register bf16 pack. Two b128 at off0 / off0^16.
#define LOADA(dst, fibase)                                                   \
    _Pragma("unroll") for (int fi = 0; fi < 4; ++fi)                         \
    _Pragma("unroll") for (int ks = 0; ks < 2; ++ks) {                       \
        const unsigned o0 = slotA + (unsigned)((((fibase) + fi) << 12)) +    \
                            (unsigned)(abase0 ^ (ks << 7));                  \
        const f32x4 lo = *(const f32x4*)((const char*)smem + o0);            \
        const f32x4 hi = *(const f32x4*)((const char*)smem + (o0 ^ 16u));    \
        bf16x8 v;                                                            \
        v[0] = (__bf16)lo[0]; v[1] = (__bf16)lo[1];                          \
        v[2] = (__bf16)lo[2]; v[3] = (__bf16)lo[3];                          \
        v[4] = (__bf16)hi[0]; v[5] = (__bf16)hi[1];                          \
        v[6] = (__bf16)hi[2]; v[7] = (__bf16)hi[3];                          \
        dst[fi][ks] = v;                                                     \
    }
#define LOADB(jhalf)                                                         \
    _Pragma("unroll") for (int fj = 0; fj < 2; ++fj)                         \
    _Pragma("unroll") for (int ks = 0; ks < 2; ++ks)                         \
        bB[fj][ks] = *(const bf16x8*)((const char*)smem + slotB + bhalf_off + \
                                      (((jhalf) + fj) << 11) + (offk0 ^ (ks << 6)));
#define MFMA8(iBase, jBase, AF)                                              \
    _Pragma("unroll") for (int fi = 0; fi < 4; ++fi)                         \
    _Pragma("unroll") for (int fj = 0; fj < 2; ++fj)                         \
    _Pragma("unroll") for (int ks = 0; ks < 2; ++ks)                         \
        acc[(iBase) + fi][(jBase) + fj] = __builtin_amdgcn_mfma_f32_16x16x32_bf16( \
            AF[fi][ks], bB[fj][ks], acc[(iBase) + fi][(jBase) + fj], 0, 0, 0);
#define SBAR __builtin_amdgcn_s_barrier()

    f32x4 acc[8][4];
#pragma unroll
    for (int i = 0; i < 8; ++i)
#pragma unroll
        for (int j = 0; j < 4; ++j)
            acc[i][j] = (f32x4){0.f, 0.f, 0.f, 0.f};

    // prologue: tile0's A+B0+B1 and tile1's B0; cold drain.
    STAGE_B0(0);
    STAGE_A(0);
    STAGE_B1(0);
    STAGE_B0(1);
    asm volatile("s_waitcnt vmcnt(0)" ::: "memory");
    SBAR;

    for (int mt = 0; mt < 4; ++mt) {
#pragma unroll 2
        for (int tk = 0; tk < 16; ++tk) {
            const int tau = (mt << 4) | tk;
            const int s1 = tau + 1, s2 = tau + 2;
            const unsigned bpar = (tk & 1) ? 98304u : 65536u;
            const unsigned slotB = bpar + slotB_q;

            bf16x8 aF0[4][2], aF1[4][2], bB[2][2];

            // ---- p0: aF0 + bB(j0-1); mfma (0-3)x(0-1)
            LOADA(aF0, 0);
            LOADB(0);
            SBAR;
            __builtin_amdgcn_s_setprio(1);
            MFMA8(0, 0, aF0);
            __builtin_amdgcn_s_setprio(0);
            SBAR;

            // ---- p1: aF1; stage B1(tau+1); mfma (4-7)x(0-1)
            LOADA(aF1, 4);
            if (s1 < 64) STAGE_B1(s1);
            SBAR;
            __builtin_amdgcn_s_setprio(1);
            MFMA8(4, 0, aF1);
            __builtin_amdgcn_s_setprio(0);
            SBAR;

            // ---- p2: bB(j2-3); stage A(tau+1); mfma (4-7)x(2-3)
            LOADB(2);
            if (s1 < 64) STAGE_A(s1);
            SBAR;
            __builtin_amdgcn_s_setprio(1);
            MFMA8(4, 2, aF1);
            __builtin_amdgcn_s_setprio(0);
            SBAR;

            // ---- p3: stage B0(tau+2); mfma (0-3)x(2-3); counted boundary wait
            if (s2 < 64) STAGE_B0(s2);
            SBAR;
            __builtin_amdgcn_s_setprio(1);
            MFMA8(0, 2, aF0);
            __builtin_amdgcn_s_setprio(0);
            if (tau < 62) {
                asm volatile("s_waitcnt vmcnt(2)" ::: "memory");
            } else if (tau == 62) {
                asm volatile("s_waitcnt vmcnt(0)" ::: "memory");
            }
            SBAR;
        }

        // ---- per-m-tile epilogue: +ph -> tanh -> *Vw -> reduce -> part
        __syncthreads();
        {
            float* red = (float*)(smem + 131072);
            const int bidx = mgrp >> 1;
            const int colg = lane & 15;
            const int rowq = (lane >> 4) << 2;
            float vw[4], phv[4];
#pragma unroll
            for (int j = 0; j < 4; ++j) {
                int u = col0 + wn * 64 + j * 16 + colg;
                vw[j] = Vw[u];
                phv[j] = ph[bidx * UDIM + u];
            }
#pragma unroll
            for (int i = 0; i < 8; ++i) {
#pragma unroll
                for (int r = 0; r < 4; ++r) {
                    float s = 0.f;
#pragma unroll
                    for (int j = 0; j < 4; ++j) {
                        float pe = acc[i][j][r] + phv[j];
                        s += fast_tanh(pe) * vw[j];
                    }
                    s += __shfl_xor(s, 1);
                    s += __shfl_xor(s, 2);
                    s += __shfl_xor(s, 4);
                    s += __shfl_xor(s, 8);
                    if (colg == 0) red[wid * 128 + i * 16 + rowq + r] = s;
                }
            }
            __syncthreads();
            if (t < 256) {
                int wmr = t >> 7;
                int rl = t & 127;
                float s = red[(wmr * 4 + 0) * 128 + rl] + red[(wmr * 4 + 1) * 128 + rl] +
                          red[(wmr * 4 + 2) * 128 + rl] + red[(wmr * 4 + 3) * 128 + rl];
                part[(size_t)tile_n * MROWS + arow0 + (mt << 8) + t] = s;
            }
        }
        if (mt < 3) {
#pragma unroll
            for (int i = 0; i < 8; ++i)
#pragma unroll
                for (int j = 0; j < 4; ++j)
                    acc[i][j] = (f32x4){0.f, 0.f, 0.f, 0.f};
        }
    }
#undef BSLOT0
#undef STAGE_B0
#undef STAGE_B1
#undef STAGE_A
#undef LOADA
#undef LOADB
#undef MFMA8
#undef SBAR
}

// ---------------- fallback GEMM (fp32 in-register convert, 16 slices) ----------------
#define BM 128
#define BN 128
#define BK 32
#define LDK 40
__global__ __launch_bounds__(256) void score_kernel_f32(
    const float* __restrict__ enc, const unsigned short* __restrict__ W1T,
    const float* __restrict__ ph, const float* __restrict__ Vw,
    float* __restrict__ part) {
    __shared__ unsigned short As[BM * LDK];
    __shared__ unsigned short Bs[BN * LDK];

    const int bx = blockIdx.x;
    const int tile_n = bx & 7;
    const int tile_m = bx >> 3;
    const int t = threadIdx.x;
    const int lane = t & 63;
    const int wid = t >> 6;
    const int wm = wid >> 1, wn = wid & 1;

    const int row0 = tile_m * BM;
    const int col0 = tile_n * BN;

    f32x4 acc[4][4];
#pragma unroll
    for (int i = 0; i < 4; ++i)
#pragma unroll
        for (int j = 0; j < 4; ++j)
            acc[i][j] = (f32x4){0.f, 0.f, 0.f, 0.f};

    const int mrow = lane & 15;
    const int kq = (lane >> 4) * 8;

    for (int kt = 0; kt < HDIM; kt += BK) {
        __syncthreads();
#pragma unroll
        for (int i = 0; i < 4; ++i) {
            int ci = t + 256 * i;
            int r = ci >> 3;
            int kc = (ci & 7) * 4;
            const float4 f = *(const float4*)(enc + (size_t)(row0 + r) * HDIM + kt + kc);
            ushort4 h;
            h.x = f2bf(f.x); h.y = f2bf(f.y); h.z = f2bf(f.z); h.w = f2bf(f.w);
            *(ushort4*)(As + r * LDK + kc) = h;
        }
#pragma unroll
        for (int i = 0; i < 2; ++i) {
            int ci = t + 256 * i;
            int r = ci >> 2;
            int kc = (ci & 3) * 8;
            const uint4 v = *(const uint4*)(W1T + (size_t)(col0 + r) * HDIM + kt + kc);
            *(uint4*)(Bs + r * LDK + kc) = v;
        }
        __syncthreads();

        bf16x8 a[4], bb[4];
#pragma unroll
        for (int i = 0; i < 4; ++i)
            a[i] = *reinterpret_cast<const bf16x8*>(As + (wm * 64 + i * 16 + mrow) * LDK + kq);
#pragma unroll
        for (int j = 0; j < 4; ++j)
            bb[j] = *reinterpret_cast<const bf16x8*>(Bs + (wn * 64 + j * 16 + mrow) * LDK + kq);
#pragma unroll
        for (int i = 0; i < 4; ++i)
#pragma unroll
            for (int j = 0; j < 4; ++j)
                acc[i][j] = __builtin_amdgcn_mfma_f32_16x16x32_bf16(a[i], bb[j], acc[i][j], 0, 0, 0);
    }

    const int b = row0 >> 11;
    const int colg = lane & 15;
    const int rowq = (lane >> 4) * 4;
    float vw[4], phv[4];
#pragma unroll
    for (int j = 0; j < 4; ++j) {
        int u = col0 + wn * 64 + j * 16 + colg;
        vw[j] = Vw[u];
        phv[j] = ph[b * UDIM + u];
    }
#pragma unroll
    for (int i = 0; i < 4; ++i) {
#pragma unroll
        for (int r = 0; r < 4; ++r) {
            float s = 0.f;
#pragma unroll
            for (int j = 0; j < 4; ++j) {
                float pe = acc[i][j][r] + phv[j];
                s += fast_tanh(pe) * vw[j];
            }
            s += __shfl_xor(s, 1);
            s += __shfl_xor(s, 2);
            s += __shfl_xor(s, 4);
            s += __shfl_xor(s, 8);
            if (colg == 0) {
                int row = row0 + wm * 64 + i * 16 + rowq + r;
                part[(size_t)(tile_n * 2 + wn) * MROWS + row] = s;
            }
        }
    }
}

// ---------------- final: sum partial slices + softmax over s ----------------
__global__ void softmax4_kernel(const float* __restrict__ part, float* __restrict__ out) {
    int b = blockIdx.x;
    int t = threadIdx.x;   // 256
    __shared__ float sred[4];
    float v[8];
    float lmax = -3.4e38f;
#pragma unroll
    for (int i = 0; i < 8; ++i) {
        int s = t + i * 256;
        float sum = 0.f;
#pragma unroll
        for (int p = 0; p < 4; ++p) sum += part[(size_t)p * MROWS + b * SDIM + s];
        v[i] = sum;
        lmax = fmaxf(lmax, sum);
    }
#pragma unroll
    for (int off = 1; off < 64; off <<= 1) lmax = fmaxf(lmax, __shfl_xor(lmax, off));
    if ((t & 63) == 0) sred[t >> 6] = lmax;
    __syncthreads();
    float bmax = fmaxf(fmaxf(sred[0], sred[1]), fmaxf(sred[2], sred[3]));
    __syncthreads();
    float lsum = 0.f;
#pragma unroll
    for (int i = 0; i < 8; ++i) {
        v[i] = expf(v[i] - bmax);
        lsum += v[i];
    }
#pragma unroll
    for (int off = 1; off < 64; off <<= 1) lsum += __shfl_xor(lsum, off);
    if ((t & 63) == 0) sred[t >> 6] = lsum;
    __syncthreads();
    float inv = 1.0f / (sred[0] + sred[1] + sred[2] + sred[3]);
#pragma unroll
    for (int i = 0; i < 8; ++i) out[b * SDIM + t + i * 256] = v[i] * inv;
}

__global__ void softmax16_kernel(const float* __restrict__ part, float* __restrict__ out) {
    int b = blockIdx.x;
    int t = threadIdx.x;   // 256
    __shared__ float sred[4];
    float v[8];
    float lmax = -3.4e38f;
#pragma unroll
    for (int i = 0; i < 8; ++i) {
        int s = t + i * 256;
        float sum = 0.f;
#pragma unroll
        for (int p = 0; p < 16; ++p) sum += part[(size_t)p * MROWS + b * SDIM + s];
        v[i] = sum;
        lmax = fmaxf(lmax, sum);
    }
#pragma unroll
    for (int off = 1; off < 64; off <<= 1) lmax = fmaxf(lmax, __shfl_xor(lmax, off));
    if ((t & 63) == 0) sred[t >> 6] = lmax;
    __syncthreads();
    float bmax = fmaxf(fmaxf(sred[0], sred[1]), fmaxf(sred[2], sred[3]));
    __syncthreads();
    float lsum = 0.f;
#pragma unroll
    for (int i = 0; i < 8; ++i) {
        v[i] = expf(v[i] - bmax);
        lsum += v[i];
    }
#pragma unroll
    for (int off = 1; off < 64; off <<= 1) lsum += __shfl_xor(lsum, off);
    if ((t & 63) == 0) sred[t >> 6] = lsum;
    __syncthreads();
    float inv = 1.0f / (sred[0] + sred[1] + sred[2] + sred[3]);
#pragma unroll
    for (int i = 0; i < 8; ++i) out[b * SDIM + t + i * 256] = v[i] * inv;
}

extern "C" void kernel_launch(void* const* d_in, const int* in_sizes, int n_in,
                              void* d_out, int out_size, void* d_ws, size_t ws_size,
                              hipStream_t stream) {
    const float* enc = (const float*)d_in[0];
    const float* hn  = (const float*)d_in[1];
    const float* W1  = (const float*)d_in[2];
    const float* W1b = (const float*)d_in[3];
    const float* W2  = (const float*)d_in[4];
    const float* W2b = (const float*)d_in[5];
    const float* Vw  = (const float*)d_in[6];
    // d_in[7] = V_b: softmax is shift-invariant per batch -> exactly cancels.
    float* out = (float*)d_out;

    char* ws = (char*)d_ws;
    // main path: W1T 2MB | ph 128K | php 1MB | part (4 slices) 1MB
    const size_t NEED = (2u << 20) + (128u << 10) + (1u << 20) + (1u << 20);

    if (ws_size >= NEED + (1u << 20)) {
        unsigned short* W1T = (unsigned short*)ws;
        float* ph   = (float*)(ws + (2u << 20));
        float* php  = (float*)(ws + (2u << 20) + (128u << 10));
        float* part = (float*)(ws + (2u << 20) + (128u << 10) + (1u << 20));

        w1t_kernel<<<dim3(32, 32), dim3(32, 8), 0, stream>>>(W1, W1T);
        php_kernel<<<dim3(4, 32, 8), 256, 0, stream>>>(hn, W2, php);
        ph_combine<<<128, 256, 0, stream>>>(php, W1b, W2b, ph);
        score_kernel3<<<dim3(256), 512, 0, stream>>>(enc, W1T, ph, Vw, part);
        softmax4_kernel<<<32, 256, 0, stream>>>(part, out);
    } else {
        unsigned short* W1T = (unsigned short*)ws;
        float* ph   = (float*)(ws + (2u << 20));
        float* php  = (float*)(ws + (2u << 20) + (128u << 10));
        float* part = (float*)(ws + (2u << 20) + (128u << 10) + (1u << 20));

        w1t_kernel<<<dim3(32, 32), dim3(32, 8), 0, stream>>>(W1, W1T);
        php_kernel<<<dim3(4, 32, 8), 256, 0, stream>>>(hn, W2, php);
        ph_combine<<<128, 256, 0, stream>>>(php, W1b, W2b, ph);
        score_kernel_f32<<<dim3(4096), 256, 0, stream>>>(enc, W1T, ph, Vw, part);
        softmax16_kernel<<<32, 256, 0, stream>>>(part, out);
    }
}